// Round 3
// baseline (652.420 us; speedup 1.0000x reference)
//
#include <hip/hip_runtime.h>
#include <hip/hip_cooperative_groups.h>
#include <math.h>

namespace cg = cooperative_groups;

#define N_INPC 3
#define N_HID 64
#define N_OUTC 10
#define SEQ_LEN 8
#define N_ROLL 16
#define DT 0.042f
#define GAMMA 2.7f
#define EPSC 4.7f
#define HH 12
#define WW 10
#define NPIX 120
#define BATCH 16
#define NC 128
#define NK 1152

typedef __attribute__((ext_vector_type(8))) short short8;
typedef __attribute__((ext_vector_type(4))) float f32x4;
typedef unsigned short ushort_t;

__device__ __forceinline__ ushort_t f2bf(float v) {
  union { float f; unsigned u; } x; x.f = v;
  unsigned r = x.u + 0x7fff + ((x.u >> 16) & 1);  // round-nearest-even
  return (ushort_t)(r >> 16);
}

// ---------------------------------------------------------------------------
// Pack pw_w[o_g][c][i][j][p] (fp32, p innermost) into bf16
// Wt[p][h][ot][ks][kg][o][j], k' = ij*128 + c = ks*32 + kg*8 + j,
// o_g = h*32 + ot*16 + o. B-fragments become contiguous coalesced 16B loads.
__global__ __launch_bounds__(256) void transpose2_kernel(
    const float* __restrict__ pw_w, ushort_t* __restrict__ Wt) {
  const int t = blockIdx.x * 256 + threadIdx.x;
  if (t >= 120 * 9216) return;
  const int p = t % 120;
  const int rest = t / 120;
  const int o = rest & 15;
  const int kg = (rest >> 4) & 3;
  const int ks = (rest >> 6) % 36;
  const int hot = (rest >> 6) / 36;
  const int o_g = (hot >> 1) * 32 + (hot & 1) * 16 + o;
  const int k0 = ks * 32 + kg * 8;
  ushort_t out8[8];
#pragma unroll
  for (int j = 0; j < 8; ++j) {
    const int kp = k0 + j;
    const int ij = kp >> 7;
    const int c = kp & 127;
    out8[j] = f2bf(pw_w[((size_t)o_g * NK + c * 9 + ij) * NPIX + p]);
  }
  uint4 pack;
  pack.x = (unsigned)out8[0] | ((unsigned)out8[1] << 16);
  pack.y = (unsigned)out8[2] | ((unsigned)out8[3] << 16);
  pack.z = (unsigned)out8[4] | ((unsigned)out8[5] << 16);
  pack.w = (unsigned)out8[6] | ((unsigned)out8[7] << 16);
  *(uint4*)(Wt + ((size_t)p * 9216 + rest) * 8) = pack;
}

// ---------------------------------------------------------------------------
// Read-in conv (EDGE pad) -> fp32 master Sm + bf16 Sg, layout [pix][b][c],
// c in [0,64) = hz, [64,128) = hy.
__global__ __launch_bounds__(256) void readin2_kernel(
    const float* __restrict__ x, const float* __restrict__ rw,
    const float* __restrict__ rb, float* __restrict__ Sm,
    ushort_t* __restrict__ Sg) {
  const int n = blockIdx.x * 256 + threadIdx.x;
  if (n >= BATCH * NC * NPIX) return;
  const int p = n % NPIX;
  const int oc = (n / NPIX) & 127;
  const int b = n / (NPIX * NC);
  const int ph = p / WW, pw_ = p % WW;
  float acc = rb[oc];
  for (int ch = 0; ch < SEQ_LEN * N_INPC; ++ch) {
    const int tt = ch / N_INPC, ic = ch % N_INPC;
    const float* xb = x + (((tt * BATCH + b) * N_INPC + ic) * HH) * WW;
    const float* wb = rw + (oc * (SEQ_LEN * N_INPC) + ch) * 9;
#pragma unroll
    for (int di = 0; di < 3; ++di) {
      int ih = ph + di - 1;
      ih = ih < 0 ? 0 : (ih > HH - 1 ? HH - 1 : ih);
#pragma unroll
      for (int dj = 0; dj < 3; ++dj) {
        int iw = pw_ + dj - 1;
        iw = iw < 0 ? 0 : (iw > WW - 1 ? WW - 1 : iw);
        acc += xb[ih * WW + iw] * wb[di * 3 + dj];
      }
    }
  }
  const int sc = (oc < 64) ? (64 + oc) : (oc - 64);
  const size_t idx = ((size_t)(p * BATCH + b)) * NC + sc;
  Sm[idx] = acc;
  Sg[idx] = f2bf(acc);
}

// ---------------------------------------------------------------------------
// Persistent fused rollout: 240 WGs = (pixel, o-half), 4 waves each.
// B-fragments live in registers for all 16 steps; fp32 master state lives in
// registers of the owning lanes (waves 0,1); bf16 state ping-pongs via global
// for the 3x3 neighbor exchange; grid.sync() between steps.
__global__ __launch_bounds__(256, 1) void persist_kernel(
    const ushort_t* __restrict__ Wt, ushort_t* __restrict__ SgA,
    ushort_t* __restrict__ SgB, float* __restrict__ Sm,
    const float* __restrict__ pwb) {
  cg::grid_group grid = cg::this_grid();
  __shared__ short8 SA[2304];   // 36,864 B A-patch, XOR-swizzled
  __shared__ f32x4 red[128];    //  2,048 B cross-wave partials
  const int wg = blockIdx.x, p = wg >> 1, h = wg & 1;
  const int ph = p / WW, pw_ = p % WW;
  const int tid = threadIdx.x, wv = tid >> 6, l = tid & 63;
  const int ot = wv & 1, kq = wv >> 1;
  const int kg = l >> 4, c16 = l & 15;
  const int o_g = h * 32 + ot * 16 + c16;

  // ---- prologue: B fragments -> registers (72 VGPRs, held entire kernel)
  short8 breg[18];
  {
    const short8* __restrict__ WB =
        (const short8*)Wt + ((size_t)((p * 2 + h) * 2 + ot)) * 2304 + kg * 16 + c16;
#pragma unroll
    for (int j = 0; j < 18; ++j) breg[j] = WB[(size_t)(kq * 18 + j) * 64];
  }
  const float pb = pwb[o_g * NPIX + p];

  // ---- fp32 master state in registers (waves 0,1: 4 batches x 1 out each)
  const int b0 = (l >> 4) * 4;
  float hzr[4], hyr[4];
  if (wv < 2) {
#pragma unroll
    for (int r = 0; r < 4; ++r) {
      const size_t iz = ((size_t)(p * BATCH + b0 + r)) * NC + o_g;
      hzr[r] = Sm[iz];
      hyr[r] = Sm[iz + 64];
    }
  }

  const int ab = tid >> 4, am = tid & 15;   // A-build: batch, c-octet
  const int abm = ab * NC + am * 8;
  ushort_t* sgbuf[2] = {SgA, SgB};

  for (int s = 0; s < N_ROLL; ++s) {
    const ushort_t* __restrict__ sgc = sgbuf[s & 1];
    ushort_t* __restrict__ sgn = sgbuf[(s + 1) & 1];

    // ---- A build: A[b][k'] = Sg[neighbor(q)][b][c], zero-pad
#pragma unroll
    for (int q = 0; q < 9; ++q) {
      const int ih = ph + q / 3 - 1, iw = pw_ + q % 3 - 1;
      short8 v = {0, 0, 0, 0, 0, 0, 0, 0};
      if ((unsigned)ih < (unsigned)HH && (unsigned)iw < (unsigned)WW)
        v = *(const short8*)(sgc + (size_t)(ih * WW + iw) * (BATCH * NC) + abm);
      const int row = q * 16 + am;
      SA[row * 16 + (ab ^ am)] = v;
    }
    __syncthreads();

    // ---- 18 MFMAs from LDS A + register B
    f32x4 acc0 = {0.f, 0.f, 0.f, 0.f}, acc1 = {0.f, 0.f, 0.f, 0.f};
#pragma unroll
    for (int ii = 0; ii < 9; ++ii) {
      const int ks0 = kq * 18 + ii * 2;
      {
        const int row = ks0 * 4 + kg;
        acc0 = __builtin_amdgcn_mfma_f32_16x16x32_bf16(
            SA[row * 16 + (c16 ^ (row & 15))], breg[ii * 2], acc0, 0, 0, 0);
      }
      {
        const int row = (ks0 + 1) * 4 + kg;
        acc1 = __builtin_amdgcn_mfma_f32_16x16x32_bf16(
            SA[row * 16 + (c16 ^ (row & 15))], breg[ii * 2 + 1], acc1, 0, 0, 0);
      }
    }
    f32x4 acc = acc0 + acc1;

    // ---- cross-wave k-reduce + fused state update (waves 0,1)
    if (wv >= 2) red[(wv - 2) * 64 + l] = acc;
    __syncthreads();
    if (wv < 2) {
      acc += red[wv * 64 + l];
#pragma unroll
      for (int r = 0; r < 4; ++r) {
        const float pre = acc[r] + pb;
        const float hz = hzr[r], hy = hyr[r];
        const float hzn = hz + DT * (tanhf(pre) - GAMMA * hy - EPSC * hz);
        const float hyn = hy + DT * hzn;
        hzr[r] = hzn;
        hyr[r] = hyn;
        const size_t iz = ((size_t)(p * BATCH + b0 + r)) * NC + o_g;
        sgn[iz] = f2bf(hzn);
        sgn[iz + 64] = f2bf(hyn);
      }
    }
    grid.sync();
  }

  // ---- epilogue: fp32 state back to global for readout
  if (wv < 2) {
#pragma unroll
    for (int r = 0; r < 4; ++r) {
      const size_t iz = ((size_t)(p * BATCH + b0 + r)) * NC + o_g;
      Sm[iz] = hzr[r];
      Sm[iz + 64] = hyr[r];
    }
  }
}

// ---------------------------------------------------------------------------
__global__ __launch_bounds__(256) void readout2_kernel(
    const float* __restrict__ Sm, const float* __restrict__ row,
    const float* __restrict__ rob, float* __restrict__ out) {
  const int n = blockIdx.x * 256 + threadIdx.x;
  if (n >= BATCH * N_OUTC * NPIX) return;
  const int p = n % NPIX;
  const int o = (n / NPIX) % N_OUTC;
  const int b = n / (NPIX * N_OUTC);
  float acc = rob[o];
  const float* hy = Sm + ((size_t)(p * BATCH + b)) * NC + 64;
#pragma unroll 8
  for (int c = 0; c < 64; ++c) acc += hy[c] * row[o * 64 + c];
  out[n] = acc;
}

// ---------------------------------------------------------------------------
extern "C" void kernel_launch(void* const* d_in, const int* in_sizes, int n_in,
                              void* d_out, int out_size, void* d_ws, size_t ws_size,
                              hipStream_t stream) {
  const float* x         = (const float*)d_in[0];
  const float* readin_w  = (const float*)d_in[1];
  const float* readin_b  = (const float*)d_in[2];
  const float* pw_w      = (const float*)d_in[3];
  const float* pw_b      = (const float*)d_in[4];
  const float* readout_w = (const float*)d_in[5];
  const float* readout_b = (const float*)d_in[6];
  float* out = (float*)d_out;

  ushort_t* Wt  = (ushort_t*)d_ws;              // 8,847,360 bf16 = 17.7 MB
  ushort_t* Sg0 = Wt + (size_t)120 * 9216 * 8;  // 245,760 bf16
  ushort_t* Sg1 = Sg0 + 245760;
  float*    Sm0 = (float*)(Sg1 + 245760);       // 245,760 f32

  transpose2_kernel<<<4320, 256, 0, stream>>>(pw_w, Wt);
  readin2_kernel<<<(BATCH * NC * NPIX + 255) / 256, 256, 0, stream>>>(
      x, readin_w, readin_b, Sm0, Sg0);

  {
    const ushort_t* aWt = Wt;
    ushort_t* aSgA = Sg0;
    ushort_t* aSgB = Sg1;
    float* aSm = Sm0;
    const float* aPwb = pw_b;
    void* args[] = {(void*)&aWt, (void*)&aSgA, (void*)&aSgB,
                    (void*)&aSm, (void*)&aPwb};
    hipLaunchCooperativeKernel((const void*)persist_kernel, dim3(NPIX * 2),
                               dim3(256), args, 0, stream);
  }

  readout2_kernel<<<(BATCH * N_OUTC * NPIX + 255) / 256, 256, 0, stream>>>(
      Sm0, readout_w, readout_b, out);
}

// Round 4
// 528.217 us; speedup vs baseline: 1.2351x; 1.2351x over previous
//
#include <hip/hip_runtime.h>
#include <hip/hip_cooperative_groups.h>
#include <math.h>

#define N_INPC 3
#define N_HID 64
#define N_OUTC 10
#define SEQ_LEN 8
#define N_ROLL 16
#define DT 0.042f
#define GAMMA 2.7f
#define EPSC 4.7f
#define HH 12
#define WW 10
#define NPIX 120
#define BATCH 16
#define NC 128
#define NK 1152

typedef __attribute__((ext_vector_type(8))) short short8;
typedef __attribute__((ext_vector_type(4))) float f32x4;
typedef unsigned short ushort_t;

__device__ __forceinline__ ushort_t f2bf(float v) {
  union { float f; unsigned u; } x; x.f = v;
  unsigned r = x.u + 0x7fff + ((x.u >> 16) & 1);  // round-nearest-even
  return (ushort_t)(r >> 16);
}

// ---------------------------------------------------------------------------
// Pack pw_w[o_g][c][i][j][p] (fp32, p innermost) into bf16
// Wt[p][h][ot][ks][kg][o][j], k' = ij*128 + c = ks*32 + kg*8 + j,
// o_g = h*32 + ot*16 + o. B-fragments become contiguous coalesced 16B loads.
__global__ __launch_bounds__(256) void transpose2_kernel(
    const float* __restrict__ pw_w, ushort_t* __restrict__ Wt) {
  const int t = blockIdx.x * 256 + threadIdx.x;
  if (t >= 120 * 9216) return;
  const int p = t % 120;
  const int rest = t / 120;
  const int o = rest & 15;
  const int kg = (rest >> 4) & 3;
  const int ks = (rest >> 6) % 36;
  const int hot = (rest >> 6) / 36;
  const int o_g = (hot >> 1) * 32 + (hot & 1) * 16 + o;
  const int k0 = ks * 32 + kg * 8;
  ushort_t out8[8];
#pragma unroll
  for (int j = 0; j < 8; ++j) {
    const int kp = k0 + j;
    const int ij = kp >> 7;
    const int c = kp & 127;
    out8[j] = f2bf(pw_w[((size_t)o_g * NK + c * 9 + ij) * NPIX + p]);
  }
  uint4 pack;
  pack.x = (unsigned)out8[0] | ((unsigned)out8[1] << 16);
  pack.y = (unsigned)out8[2] | ((unsigned)out8[3] << 16);
  pack.z = (unsigned)out8[4] | ((unsigned)out8[5] << 16);
  pack.w = (unsigned)out8[6] | ((unsigned)out8[7] << 16);
  *(uint4*)(Wt + ((size_t)p * 9216 + rest) * 8) = pack;
}

// ---------------------------------------------------------------------------
// Read-in conv (EDGE pad) -> fp32 master Sm + bf16 Sg, layout [pix][b][c],
// c in [0,64) = hz, [64,128) = hy.
__global__ __launch_bounds__(256) void readin2_kernel(
    const float* __restrict__ x, const float* __restrict__ rw,
    const float* __restrict__ rb, float* __restrict__ Sm,
    ushort_t* __restrict__ Sg) {
  const int n = blockIdx.x * 256 + threadIdx.x;
  if (n >= BATCH * NC * NPIX) return;
  const int p = n % NPIX;
  const int oc = (n / NPIX) & 127;
  const int b = n / (NPIX * NC);
  const int ph = p / WW, pw_ = p % WW;
  float acc = rb[oc];
  for (int ch = 0; ch < SEQ_LEN * N_INPC; ++ch) {
    const int tt = ch / N_INPC, ic = ch % N_INPC;
    const float* xb = x + (((tt * BATCH + b) * N_INPC + ic) * HH) * WW;
    const float* wb = rw + (oc * (SEQ_LEN * N_INPC) + ch) * 9;
#pragma unroll
    for (int di = 0; di < 3; ++di) {
      int ih = ph + di - 1;
      ih = ih < 0 ? 0 : (ih > HH - 1 ? HH - 1 : ih);
#pragma unroll
      for (int dj = 0; dj < 3; ++dj) {
        int iw = pw_ + dj - 1;
        iw = iw < 0 ? 0 : (iw > WW - 1 ? WW - 1 : iw);
        acc += xb[ih * WW + iw] * wb[di * 3 + dj];
      }
    }
  }
  const int sc = (oc < 64) ? (64 + oc) : (oc - 64);
  const size_t idx = ((size_t)(p * BATCH + b)) * NC + sc;
  Sm[idx] = acc;
  Sg[idx] = f2bf(acc);
}

// ---------------------------------------------------------------------------
// Persistent fused rollout, flag-synced (NO grid.sync).
// 240 WGs = (pixel, o-half), 4 waves. Weights + fp32 state in registers.
// Producer: state stores -> __syncthreads (vmcnt drained) -> tid0 RELEASE
// flag store (L2 writeback => cross-XCD visible). Consumer: lanes 0..17
// ACQUIRE-spin on <=18 neighbor flags (L2 inv per poll => progress), then
// A-build reads fresh states. Ping-pong WAR safe: writer of S_{s+2} at q
// first saw all q-neighbors' flags >= s+1, i.e. they finished reading S_s.
// Flags start at 0xAAAAAAAA (harness poison) = negative => not-ready. Max
// flag value written is 15 (s+1 for s<15); step-s spin target is s <= 15.
__global__ __launch_bounds__(256, 1) void persist3_kernel(
    const ushort_t* __restrict__ Wt, ushort_t* __restrict__ SgA,
    ushort_t* __restrict__ SgB, float* __restrict__ Sm,
    const float* __restrict__ pwb, int* __restrict__ flags) {
  __shared__ short8 SA[2304];   // 36,864 B A-patch, XOR-swizzled
  __shared__ f32x4 red[128];    //  2,048 B cross-wave partials
  const int wg = blockIdx.x, p = wg >> 1, h = wg & 1;
  const int ph = p / WW, pw_ = p % WW;
  const int tid = threadIdx.x, wv = tid >> 6, l = tid & 63;
  const int ot = wv & 1, kq = wv >> 1;
  const int kg = l >> 4, c16 = l & 15;
  const int o_g = h * 32 + ot * 16 + c16;

  // ---- spin metadata: lane i<18 watches neighbor (i>>1)'s half (i&1)
  bool relevant = false;
  int faddr = 0;
  if (l < 18) {
    const int q = l >> 1;
    const int nh = ph + q / 3 - 1, nw = pw_ + q % 3 - 1;
    if ((unsigned)nh < (unsigned)HH && (unsigned)nw < (unsigned)WW) {
      relevant = true;
      faddr = ((nh * WW + nw) << 1) | (l & 1);
    }
  }

  // ---- prologue: B fragments -> registers (72 VGPRs, held entire kernel)
  short8 breg[18];
  {
    const short8* __restrict__ WB =
        (const short8*)Wt + ((size_t)((p * 2 + h) * 2 + ot)) * 2304 + kg * 16 + c16;
#pragma unroll
    for (int j = 0; j < 18; ++j) breg[j] = WB[(size_t)(kq * 18 + j) * 64];
  }
  const float pb = pwb[o_g * NPIX + p];

  // ---- fp32 master state in registers (waves 0,1: 4 batches x 1 out each)
  const int b0 = (l >> 4) * 4;
  float hzr[4], hyr[4];
  if (wv < 2) {
#pragma unroll
    for (int r = 0; r < 4; ++r) {
      const size_t iz = ((size_t)(p * BATCH + b0 + r)) * NC + o_g;
      hzr[r] = Sm[iz];
      hyr[r] = Sm[iz + 64];
    }
  }

  const int ab = tid >> 4, am = tid & 15;   // A-build: batch, c-octet
  const int abm = ab * NC + am * 8;

  for (int s = 0; s < N_ROLL; ++s) {
    const ushort_t* __restrict__ sgc = (s & 1) ? SgB : SgA;
    ushort_t* __restrict__ sgn = (s & 1) ? SgA : SgB;

    // ---- wait for neighbors' S_s (every wave spins; no divergence: all
    // 64 lanes in the loop, lanes >=18 or OOB always "ready")
    if (s > 0) {
      while (true) {
        const int f = __hip_atomic_load(flags + faddr, __ATOMIC_ACQUIRE,
                                        __HIP_MEMORY_SCOPE_AGENT);
        if (__all(!relevant || f >= s)) break;
      }
    }

    // ---- A build: A[b][k'] = Sg[neighbor(q)][b][c], zero-pad
#pragma unroll
    for (int q = 0; q < 9; ++q) {
      const int ih = ph + q / 3 - 1, iw = pw_ + q % 3 - 1;
      short8 v = {0, 0, 0, 0, 0, 0, 0, 0};
      if ((unsigned)ih < (unsigned)HH && (unsigned)iw < (unsigned)WW)
        v = *(const short8*)(sgc + (size_t)(ih * WW + iw) * (BATCH * NC) + abm);
      const int row = q * 16 + am;
      SA[row * 16 + (ab ^ am)] = v;
    }
    __syncthreads();

    // ---- 18 MFMAs from LDS A + register B
    f32x4 acc0 = {0.f, 0.f, 0.f, 0.f}, acc1 = {0.f, 0.f, 0.f, 0.f};
#pragma unroll
    for (int ii = 0; ii < 9; ++ii) {
      const int ks0 = kq * 18 + ii * 2;
      {
        const int row = ks0 * 4 + kg;
        acc0 = __builtin_amdgcn_mfma_f32_16x16x32_bf16(
            SA[row * 16 + (c16 ^ (row & 15))], breg[ii * 2], acc0, 0, 0, 0);
      }
      {
        const int row = (ks0 + 1) * 4 + kg;
        acc1 = __builtin_amdgcn_mfma_f32_16x16x32_bf16(
            SA[row * 16 + (c16 ^ (row & 15))], breg[ii * 2 + 1], acc1, 0, 0, 0);
      }
    }
    f32x4 acc = acc0 + acc1;

    // ---- cross-wave k-reduce + fused state update (waves 0,1)
    if (wv >= 2) red[(wv - 2) * 64 + l] = acc;
    __syncthreads();
    if (wv < 2) {
      acc += red[wv * 64 + l];
#pragma unroll
      for (int r = 0; r < 4; ++r) {
        const float pre = acc[r] + pb;
        const float hz = hzr[r], hy = hyr[r];
        const float hzn = hz + DT * (tanhf(pre) - GAMMA * hy - EPSC * hz);
        const float hyn = hy + DT * hzn;
        hzr[r] = hzn;
        hyr[r] = hyn;
        const size_t iz = ((size_t)(p * BATCH + b0 + r)) * NC + o_g;
        sgn[iz] = f2bf(hzn);
        sgn[iz + 64] = f2bf(hyn);
      }
    }
    if (s < N_ROLL - 1) {
      __syncthreads();  // all state stores drained (vmcnt(0) before barrier)
      if (tid == 0)
        __hip_atomic_store(flags + wg, s + 1, __ATOMIC_RELEASE,
                           __HIP_MEMORY_SCOPE_AGENT);
    }
  }

  // ---- epilogue: fp32 state back to global for readout
  if (wv < 2) {
#pragma unroll
    for (int r = 0; r < 4; ++r) {
      const size_t iz = ((size_t)(p * BATCH + b0 + r)) * NC + o_g;
      Sm[iz] = hzr[r];
      Sm[iz + 64] = hyr[r];
    }
  }
}

// ---------------------------------------------------------------------------
__global__ __launch_bounds__(256) void readout2_kernel(
    const float* __restrict__ Sm, const float* __restrict__ row,
    const float* __restrict__ rob, float* __restrict__ out) {
  const int n = blockIdx.x * 256 + threadIdx.x;
  if (n >= BATCH * N_OUTC * NPIX) return;
  const int p = n % NPIX;
  const int o = (n / NPIX) % N_OUTC;
  const int b = n / (NPIX * N_OUTC);
  float acc = rob[o];
  const float* hy = Sm + ((size_t)(p * BATCH + b)) * NC + 64;
#pragma unroll 8
  for (int c = 0; c < 64; ++c) acc += hy[c] * row[o * 64 + c];
  out[n] = acc;
}

// ---------------------------------------------------------------------------
extern "C" void kernel_launch(void* const* d_in, const int* in_sizes, int n_in,
                              void* d_out, int out_size, void* d_ws, size_t ws_size,
                              hipStream_t stream) {
  const float* x         = (const float*)d_in[0];
  const float* readin_w  = (const float*)d_in[1];
  const float* readin_b  = (const float*)d_in[2];
  const float* pw_w      = (const float*)d_in[3];
  const float* pw_b      = (const float*)d_in[4];
  const float* readout_w = (const float*)d_in[5];
  const float* readout_b = (const float*)d_in[6];
  float* out = (float*)d_out;

  ushort_t* Wt  = (ushort_t*)d_ws;              // 8,847,360 bf16 = 17.7 MB
  ushort_t* Sg0 = Wt + (size_t)120 * 9216 * 8;  // 245,760 bf16
  ushort_t* Sg1 = Sg0 + 245760;
  float*    Sm0 = (float*)(Sg1 + 245760);       // 245,760 f32
  int*      flg = (int*)(Sm0 + 245760);         // 240 ints (poison = negative)

  transpose2_kernel<<<4320, 256, 0, stream>>>(pw_w, Wt);
  readin2_kernel<<<(BATCH * NC * NPIX + 255) / 256, 256, 0, stream>>>(
      x, readin_w, readin_b, Sm0, Sg0);

  {
    const ushort_t* aWt = Wt;
    ushort_t* aSgA = Sg0;
    ushort_t* aSgB = Sg1;
    float* aSm = Sm0;
    const float* aPwb = pw_b;
    int* aFlg = flg;
    void* args[] = {(void*)&aWt, (void*)&aSgA, (void*)&aSgB,
                    (void*)&aSm, (void*)&aPwb, (void*)&aFlg};
    hipLaunchCooperativeKernel((const void*)persist3_kernel, dim3(NPIX * 2),
                               dim3(256), args, 0, stream);
  }

  readout2_kernel<<<(BATCH * N_OUTC * NPIX + 255) / 256, 256, 0, stream>>>(
      Sm0, readout_w, readout_b, out);
}

// Round 6
// 216.848 us; speedup vs baseline: 3.0086x; 2.4359x over previous
//
#include <hip/hip_runtime.h>
#include <hip/hip_cooperative_groups.h>
#include <math.h>

#define N_INPC 3
#define N_HID 64
#define N_OUTC 10
#define SEQ_LEN 8
#define N_ROLL 16
#define DT 0.042f
#define GAMMA 2.7f
#define EPSC 4.7f
#define HH 12
#define WW 10
#define NPIX 120
#define BATCH 16
#define NC 128
#define NK 1152

typedef __attribute__((ext_vector_type(8))) short short8;
typedef __attribute__((ext_vector_type(4))) float f32x4;
typedef unsigned short ushort_t;
typedef unsigned long long u64;

__device__ __forceinline__ ushort_t f2bf(float v) {
  union { float f; unsigned u; } x; x.f = v;
  unsigned r = x.u + 0x7fff + ((x.u >> 16) & 1);  // round-nearest-even
  return (ushort_t)(r >> 16);
}

// ---------------------------------------------------------------------------
// Pack pw_w[o_g][c][i][j][p] (fp32, p innermost) into bf16
// Wt[p][h][ot][ks][kg][o][j], k' = ij*128 + c = ks*32 + kg*8 + j,
// o_g = h*32 + ot*16 + o. B-fragments become contiguous coalesced 16B loads.
__global__ __launch_bounds__(256) void transpose2_kernel(
    const float* __restrict__ pw_w, ushort_t* __restrict__ Wt) {
  const int t = blockIdx.x * 256 + threadIdx.x;
  if (t >= 120 * 9216) return;
  const int p = t % 120;
  const int rest = t / 120;
  const int o = rest & 15;
  const int kg = (rest >> 4) & 3;
  const int ks = (rest >> 6) % 36;
  const int hot = (rest >> 6) / 36;
  const int o_g = (hot >> 1) * 32 + (hot & 1) * 16 + o;
  const int k0 = ks * 32 + kg * 8;
  ushort_t out8[8];
#pragma unroll
  for (int j = 0; j < 8; ++j) {
    const int kp = k0 + j;
    const int ij = kp >> 7;
    const int c = kp & 127;
    out8[j] = f2bf(pw_w[((size_t)o_g * NK + c * 9 + ij) * NPIX + p]);
  }
  uint4 pack;
  pack.x = (unsigned)out8[0] | ((unsigned)out8[1] << 16);
  pack.y = (unsigned)out8[2] | ((unsigned)out8[3] << 16);
  pack.z = (unsigned)out8[4] | ((unsigned)out8[5] << 16);
  pack.w = (unsigned)out8[6] | ((unsigned)out8[7] << 16);
  *(uint4*)(Wt + ((size_t)p * 9216 + rest) * 8) = pack;
}

// ---------------------------------------------------------------------------
// Read-in conv (EDGE pad) -> fp32 master Sm + bf16 Sg, layout [pix][b][c],
// c in [0,64) = hz, [64,128) = hy.
__global__ __launch_bounds__(256) void readin2_kernel(
    const float* __restrict__ x, const float* __restrict__ rw,
    const float* __restrict__ rb, float* __restrict__ Sm,
    ushort_t* __restrict__ Sg) {
  const int n = blockIdx.x * 256 + threadIdx.x;
  if (n >= BATCH * NC * NPIX) return;
  const int p = n % NPIX;
  const int oc = (n / NPIX) & 127;
  const int b = n / (NPIX * NC);
  const int ph = p / WW, pw_ = p % WW;
  float acc = rb[oc];
  for (int ch = 0; ch < SEQ_LEN * N_INPC; ++ch) {
    const int tt = ch / N_INPC, ic = ch % N_INPC;
    const float* xb = x + (((tt * BATCH + b) * N_INPC + ic) * HH) * WW;
    const float* wb = rw + (oc * (SEQ_LEN * N_INPC) + ch) * 9;
#pragma unroll
    for (int di = 0; di < 3; ++di) {
      int ih = ph + di - 1;
      ih = ih < 0 ? 0 : (ih > HH - 1 ? HH - 1 : ih);
#pragma unroll
      for (int dj = 0; dj < 3; ++dj) {
        int iw = pw_ + dj - 1;
        iw = iw < 0 ? 0 : (iw > WW - 1 ? WW - 1 : iw);
        acc += xb[ih * WW + iw] * wb[di * 3 + dj];
      }
    }
  }
  const int sc = (oc < 64) ? (64 + oc) : (oc - 64);
  const size_t idx = ((size_t)(p * BATCH + b)) * NC + sc;
  Sm[idx] = acc;
  Sg[idx] = f2bf(acc);
}

// ---------------------------------------------------------------------------
// Persistent fused rollout, flag-synced via RELAXED device-scope atomics
// (no acquire/release => no buffer_inv / buffer_wbl2 L2 storms).
// All cross-WG state traffic goes through L3 (coherence point) as relaxed
// AGENT-scope atomic u64 ops; ordering from the vmcnt(0) drain that
// __syncthreads performs before s_barrier (stores acked before flag post).
// Flags: one 64B line each; poison 0xAAAAAAAA = negative = not-ready.
// Ping-pong WAR safe: before overwriting S_{s-1}, the WG has observed all
// neighbor flags >= s, which certifies their step-(s-1) reads completed.
__global__ __launch_bounds__(256, 1) void persist5_kernel(
    const ushort_t* __restrict__ Wt, ushort_t* __restrict__ SgA,
    ushort_t* __restrict__ SgB, float* __restrict__ Sm,
    const float* __restrict__ pwb, int* __restrict__ flags) {
  __shared__ short8 SA[2304];        // 36,864 B A-patch, XOR-swizzled
  __shared__ f32x4 red[128];         //  2,048 B cross-wave partials
  __shared__ ushort_t tmp[16][64];   //  2,048 B bf16 state staging
  const int wg = blockIdx.x, p = wg >> 1, h = wg & 1;
  const int ph = p / WW, pw_ = p % WW;
  const int tid = threadIdx.x, wv = tid >> 6, l = tid & 63;
  const int ot = wv & 1, kq = wv >> 1;
  const int kg = l >> 4, c16 = l & 15;
  const int o_g = h * 32 + ot * 16 + c16;

  // ---- spin metadata (wave 0 only): lane i<18 -> neighbor (i>>1), half i&1
  bool relevant = false;
  int faddr = 0;
  if (wv == 0 && l < 18) {
    const int q = l >> 1;
    const int nh = ph + q / 3 - 1, nw = pw_ + q % 3 - 1;
    if ((unsigned)nh < (unsigned)HH && (unsigned)nw < (unsigned)WW) {
      relevant = true;
      faddr = (((nh * WW + nw) << 1) | (l & 1)) * 16;  // 64B-padded flags
    }
  }

  // ---- prologue: B fragments -> registers (72 VGPRs, held entire kernel)
  short8 breg[18];
  {
    const short8* __restrict__ WB =
        (const short8*)Wt + ((size_t)((p * 2 + h) * 2 + ot)) * 2304 + kg * 16 + c16;
#pragma unroll
    for (int j = 0; j < 18; ++j) breg[j] = WB[(size_t)(kq * 18 + j) * 64];
  }
  const float pb = pwb[o_g * NPIX + p];

  // ---- fp32 master state in registers (waves 0,1: 4 batches x 1 out each)
  const int b0 = (l >> 4) * 4;
  float hzr[4], hyr[4];
  if (wv < 2) {
#pragma unroll
    for (int r = 0; r < 4; ++r) {
      const size_t iz = ((size_t)(p * BATCH + b0 + r)) * NC + o_g;
      hzr[r] = Sm[iz];
      hyr[r] = Sm[iz + 64];
    }
  }

  const int ab = tid >> 4, am = tid & 15;   // A-build: batch, c-octet
  const int abm = ab * NC + am * 8;

  for (int s = 0; s < N_ROLL; ++s) {
    const ushort_t* __restrict__ sgc = (s & 1) ? SgB : SgA;
    ushort_t* __restrict__ sgn = (s & 1) ? SgA : SgB;

    // ---- B0: wait for neighbors' S_s (wave 0 spins on relaxed loads)
    if (s > 0) {
      if (wv == 0) {
        while (true) {
          int f = 0x7fffffff;
          if (relevant)
            f = __hip_atomic_load(flags + faddr, __ATOMIC_RELAXED,
                                  __HIP_MEMORY_SCOPE_AGENT);
          if (__all(!relevant || f >= s)) break;
          __builtin_amdgcn_s_sleep(1);
        }
      }
      __syncthreads();
    }

    // ---- A build: A[b][k'] = S_s[neighbor(q)][b][c] via relaxed u64 loads
#pragma unroll
    for (int q = 0; q < 9; ++q) {
      const int ih = ph + q / 3 - 1, iw = pw_ + q % 3 - 1;
      union { u64 u[2]; short8 s8; } cv;
      cv.u[0] = 0; cv.u[1] = 0;
      if ((unsigned)ih < (unsigned)HH && (unsigned)iw < (unsigned)WW) {
        const u64* src =
            (const u64*)(sgc + (size_t)(ih * WW + iw) * (BATCH * NC) + abm);
        cv.u[0] = __hip_atomic_load(src, __ATOMIC_RELAXED,
                                    __HIP_MEMORY_SCOPE_AGENT);
        cv.u[1] = __hip_atomic_load(src + 1, __ATOMIC_RELAXED,
                                    __HIP_MEMORY_SCOPE_AGENT);
      }
      const int row = q * 16 + am;
      SA[row * 16 + (ab ^ am)] = cv.s8;
    }
    __syncthreads();   // B1

    // ---- 18 MFMAs from LDS A + register B
    f32x4 acc0 = {0.f, 0.f, 0.f, 0.f}, acc1 = {0.f, 0.f, 0.f, 0.f};
#pragma unroll
    for (int ii = 0; ii < 9; ++ii) {
      const int ks0 = kq * 18 + ii * 2;
      {
        const int row = ks0 * 4 + kg;
        acc0 = __builtin_amdgcn_mfma_f32_16x16x32_bf16(
            SA[row * 16 + (c16 ^ (row & 15))], breg[ii * 2], acc0, 0, 0, 0);
      }
      {
        const int row = (ks0 + 1) * 4 + kg;
        acc1 = __builtin_amdgcn_mfma_f32_16x16x32_bf16(
            SA[row * 16 + (c16 ^ (row & 15))], breg[ii * 2 + 1], acc1, 0, 0, 0);
      }
    }
    f32x4 acc = acc0 + acc1;

    // ---- cross-wave k-reduce + fused state update (waves 0,1)
    if (wv >= 2) red[(wv - 2) * 64 + l] = acc;
    __syncthreads();   // B2
    if (wv < 2) {
      acc += red[wv * 64 + l];
#pragma unroll
      for (int r = 0; r < 4; ++r) {
        const float pre = acc[r] + pb;
        const float hz = hzr[r], hy = hyr[r];
        const float hzn = hz + DT * (tanhf(pre) - GAMMA * hy - EPSC * hz);
        const float hyn = hy + DT * hzn;
        hzr[r] = hzn;
        hyr[r] = hyn;
        tmp[b0 + r][ot * 16 + c16] = f2bf(hzn);        // hz slot (col 0..31)
        tmp[b0 + r][32 + ot * 16 + c16] = f2bf(hyn);   // hy slot (col 32..63)
      }
    }

    if (s < N_ROLL - 1) {
      __syncthreads();   // B3: tmp ready
      // ---- coalesced relaxed u64 state stores: 1 per thread
      {
        const int b = tid >> 4, zy = (tid >> 3) & 1, g = tid & 7;
        union { ushort_t us[4]; u64 u; } pk;
#pragma unroll
        for (int j = 0; j < 4; ++j) pk.us[j] = tmp[b][zy * 32 + g * 4 + j];
        u64* dst = (u64*)(sgn + (size_t)(p * BATCH + b) * NC + zy * 64 +
                          h * 32 + g * 4);
        __hip_atomic_store(dst, pk.u, __ATOMIC_RELAXED,
                           __HIP_MEMORY_SCOPE_AGENT);
      }
      __syncthreads();   // B4: vmcnt(0) drained -> stores acked at L3
      if (tid == 0)
        __hip_atomic_store(flags + wg * 16, s + 1, __ATOMIC_RELAXED,
                           __HIP_MEMORY_SCOPE_AGENT);
    }
  }

  // ---- epilogue: fp32 state back to global for readout
  if (wv < 2) {
#pragma unroll
    for (int r = 0; r < 4; ++r) {
      const size_t iz = ((size_t)(p * BATCH + b0 + r)) * NC + o_g;
      Sm[iz] = hzr[r];
      Sm[iz + 64] = hyr[r];
    }
  }
}

// ---------------------------------------------------------------------------
__global__ __launch_bounds__(256) void readout2_kernel(
    const float* __restrict__ Sm, const float* __restrict__ row,
    const float* __restrict__ rob, float* __restrict__ out) {
  const int n = blockIdx.x * 256 + threadIdx.x;
  if (n >= BATCH * N_OUTC * NPIX) return;
  const int p = n % NPIX;
  const int o = (n / NPIX) % N_OUTC;
  const int b = n / (NPIX * N_OUTC);
  float acc = rob[o];
  const float* hy = Sm + ((size_t)(p * BATCH + b)) * NC + 64;
#pragma unroll 8
  for (int c = 0; c < 64; ++c) acc += hy[c] * row[o * 64 + c];
  out[n] = acc;
}

// ---------------------------------------------------------------------------
extern "C" void kernel_launch(void* const* d_in, const int* in_sizes, int n_in,
                              void* d_out, int out_size, void* d_ws, size_t ws_size,
                              hipStream_t stream) {
  const float* x         = (const float*)d_in[0];
  const float* readin_w  = (const float*)d_in[1];
  const float* readin_b  = (const float*)d_in[2];
  const float* pw_w      = (const float*)d_in[3];
  const float* pw_b      = (const float*)d_in[4];
  const float* readout_w = (const float*)d_in[5];
  const float* readout_b = (const float*)d_in[6];
  float* out = (float*)d_out;

  ushort_t* Wt  = (ushort_t*)d_ws;              // 8,847,360 bf16 = 17.7 MB
  ushort_t* Sg0 = Wt + (size_t)120 * 9216 * 8;  // 245,760 bf16
  ushort_t* Sg1 = Sg0 + 245760;
  float*    Sm0 = (float*)(Sg1 + 245760);       // 245,760 f32
  int*      flg = (int*)(Sm0 + 245760);         // 240 x 64B-padded flags

  transpose2_kernel<<<4320, 256, 0, stream>>>(pw_w, Wt);
  readin2_kernel<<<(BATCH * NC * NPIX + 255) / 256, 256, 0, stream>>>(
      x, readin_w, readin_b, Sm0, Sg0);

  {
    const ushort_t* aWt = Wt;
    ushort_t* aSgA = Sg0;
    ushort_t* aSgB = Sg1;
    float* aSm = Sm0;
    const float* aPwb = pw_b;
    int* aFlg = flg;
    void* args[] = {(void*)&aWt, (void*)&aSgA, (void*)&aSgB,
                    (void*)&aSm, (void*)&aPwb, (void*)&aFlg};
    hipLaunchCooperativeKernel((const void*)persist5_kernel, dim3(NPIX * 2),
                               dim3(256), args, 0, stream);
  }

  readout2_kernel<<<(BATCH * N_OUTC * NPIX + 255) / 256, 256, 0, stream>>>(
      Sm0, readout_w, readout_b, out);
}

// Round 8
// 202.188 us; speedup vs baseline: 3.2268x; 1.0725x over previous
//
#include <hip/hip_runtime.h>
#include <math.h>

#define N_INPC 3
#define N_HID 64
#define N_OUTC 10
#define SEQ_LEN 8
#define N_ROLL 16
#define DT 0.042f
#define GAMMA 2.7f
#define EPSC 4.7f
#define HH 12
#define WW 10
#define NPIX 120
#define BATCH 16
#define NC 128
#define NK 1152

typedef __attribute__((ext_vector_type(8))) short short8;
typedef __attribute__((ext_vector_type(4))) float f32x4;
typedef unsigned short ushort_t;
typedef unsigned long long u64;

__device__ __forceinline__ ushort_t f2bf(float v) {
  union { float f; unsigned u; } x; x.f = v;
  unsigned r = x.u + 0x7fff + ((x.u >> 16) & 1);  // round-nearest-even
  return (ushort_t)(r >> 16);
}

// ---------------------------------------------------------------------------
// Pack pw_w[o_g][c][i][j][p] (fp32, p innermost) into bf16
// Wt[p][T][ks][kg][o][j], k' = ij*128 + c = ks*32 + kg*8 + j, o_g = T*16 + o.
// B-fragments become contiguous coalesced 16B loads. Separate kernel so the
// kernel boundary provides the cross-XCD visibility for Wt (normal stores).
__global__ __launch_bounds__(256) void transpose2_kernel(
    const float* __restrict__ pw_w, ushort_t* __restrict__ Wt) {
  const int t = blockIdx.x * 256 + threadIdx.x;
  if (t >= 120 * 9216) return;
  const int p = t % 120;
  const int rest = t / 120;
  const int o = rest & 15;
  const int kg = (rest >> 4) & 3;
  const int ks = (rest >> 6) % 36;
  const int T = (rest >> 6) / 36;           // o-tile 0..3
  const int o_g = T * 16 + o;
  const int k0 = ks * 32 + kg * 8;
  ushort_t out8[8];
#pragma unroll
  for (int j = 0; j < 8; ++j) {
    const int kp = k0 + j;
    const int ij = kp >> 7;
    const int c = kp & 127;
    out8[j] = f2bf(pw_w[((size_t)o_g * NK + c * 9 + ij) * NPIX + p]);
  }
  uint4 pack;
  pack.x = (unsigned)out8[0] | ((unsigned)out8[1] << 16);
  pack.y = (unsigned)out8[2] | ((unsigned)out8[3] << 16);
  pack.z = (unsigned)out8[4] | ((unsigned)out8[5] << 16);
  pack.w = (unsigned)out8[6] | ((unsigned)out8[7] << 16);
  *(uint4*)(Wt + ((size_t)p * 9216 + rest) * 8) = pack;
}

// ---------------------------------------------------------------------------
// One WG per pixel (120 x 512 threads, 8 waves). Everything fused:
//   readin (own pixel, fp32) -> flag 0 -> 16 steps (flag-synced, 8 neighbors)
//   -> readout (own pixel) -> d_out.
// Wave w: o-tile ot=w&3, K-half kq=w>>2. Weights (18 B-frags = 72 VGPR) and
// fp32 master state (waves 0-3) live in registers the whole kernel. Cross-WG
// state exchange: relaxed AGENT-scope u64 atomics (L3 coherence point, no
// acquire/release L2 storms — proven in R6). Flag f[p] >= s means "pixel p's
// S_s is visible at L3". Step s waits for 8 neighbor flags >= s, reads S_s,
// writes S_{s+1}, posts s+1. WAR on ping-pong safe: before overwriting
// S_{s-1}'s buffer, all neighbors showed >= s (their S_{s-1} reads done).
// Center column of A comes from LDS (tmp), not L3. Flags start poisoned
// 0xAAAAAAAA (negative) => never falsely ready.
__global__ __launch_bounds__(512, 1) void persist6_kernel(
    const ushort_t* __restrict__ Wt, ushort_t* __restrict__ SgA,
    ushort_t* __restrict__ SgB, const float* __restrict__ x,
    const float* __restrict__ rw, const float* __restrict__ rb,
    const float* __restrict__ pwb, const float* __restrict__ row,
    const float* __restrict__ rob, float* __restrict__ out,
    int* __restrict__ flags) {
  __shared__ char shraw[36864] __attribute__((aligned(16)));
  short8* SA = (short8*)shraw;                 // A-patch [144 rows][16 slots]
  float (*Sf)[128] = (float(*)[128])shraw;     // readin staging (overlay)
  float (*hyf)[64] = (float(*)[64])shraw;      // readout staging (overlay)
  __shared__ f32x4 red[256];                   // cross-wave partials (4 KB)
  __shared__ ushort_t tmp[16][128];            // own bf16 state (4 KB)

  const int p = blockIdx.x;
  const int ph = p / WW, pw_ = p % WW;
  const int tid = threadIdx.x, wv = tid >> 6, l = tid & 63;
  const int ot = wv & 3, kq = wv >> 2;
  const int kg = l >> 4, c16 = l & 15;
  const int o_g = ot * 16 + c16;
  const int b0 = (l >> 4) * 4;

  // ---- spin metadata: wave 0, lanes 0..7 watch the 8 neighbors
  bool relevant = false;
  int faddr = 0;
  if (wv == 0 && l < 8) {
    const int q = l + (l >= 4);                // skip center
    const int nh = ph + q / 3 - 1, nw = pw_ + q % 3 - 1;
    if ((unsigned)nh < (unsigned)HH && (unsigned)nw < (unsigned)WW) {
      relevant = true;
      faddr = (nh * WW + nw) * 16;             // 64B-padded flags
    }
  }

  // ================= readin (own pixel): 512 thr x 4 values =================
  {
    const int c = tid & 127;                   // state channel
    const int bq = tid >> 7;                   // batch quad
    const int oc = (c < 64) ? (64 + c) : (c - 64);  // conv channel
    int ihs[3], iws[3];
#pragma unroll
    for (int d = 0; d < 3; ++d) {
      int ih = ph + d - 1; ihs[d] = ih < 0 ? 0 : (ih > HH - 1 ? HH - 1 : ih);
      int iw = pw_ + d - 1; iws[d] = iw < 0 ? 0 : (iw > WW - 1 ? WW - 1 : iw);
    }
    float a[4];
#pragma unroll
    for (int j = 0; j < 4; ++j) a[j] = rb[oc];
    for (int ch = 0; ch < SEQ_LEN * N_INPC; ++ch) {
      const int tt = ch / N_INPC, ic = ch % N_INPC;
      const float* wb = rw + (oc * (SEQ_LEN * N_INPC) + ch) * 9;
      float w9[9];
#pragma unroll
      for (int t2 = 0; t2 < 9; ++t2) w9[t2] = wb[t2];
#pragma unroll
      for (int j = 0; j < 4; ++j) {
        const float* xb =
            x + (((size_t)(tt * BATCH + bq * 4 + j) * N_INPC + ic) * HH) * WW;
        float s = 0.f;
#pragma unroll
        for (int di = 0; di < 3; ++di)
#pragma unroll
          for (int dj = 0; dj < 3; ++dj)
            s += xb[ihs[di] * WW + iws[dj]] * w9[di * 3 + dj];
        a[j] += s;
      }
    }
#pragma unroll
    for (int j = 0; j < 4; ++j) Sf[bq * 4 + j][c] = a[j];
  }
  __syncthreads();

  // ---- owners (waves 0-3) pick up fp32 master state + write tmp (bf16)
  float hzr[4], hyr[4];
  if (wv < 4) {
#pragma unroll
    for (int r = 0; r < 4; ++r) {
      hzr[r] = Sf[b0 + r][o_g];
      hyr[r] = Sf[b0 + r][64 + o_g];
      tmp[b0 + r][o_g] = f2bf(hzr[r]);
      tmp[b0 + r][64 + o_g] = f2bf(hyr[r]);
    }
  }
  __syncthreads();

  // ---- publish S_0 (coalesced relaxed u64 atomic stores) + flag 0
  {
    const int b = tid >> 5, ci = tid & 31;
    union { ushort_t us[4]; u64 u; } pk;
#pragma unroll
    for (int j2 = 0; j2 < 4; ++j2) pk.us[j2] = tmp[b][ci * 4 + j2];
    u64* dst = (u64*)(SgA + ((size_t)(p * BATCH + b)) * NC + ci * 4);
    __hip_atomic_store(dst, pk.u, __ATOMIC_RELAXED, __HIP_MEMORY_SCOPE_AGENT);
  }
  __syncthreads();  // vmcnt(0) drained -> stores acked at L3
  if (tid == 0)
    __hip_atomic_store(flags + p * 16, 0, __ATOMIC_RELAXED,
                       __HIP_MEMORY_SCOPE_AGENT);

  // ================= weights -> registers (held all 16 steps) ===============
  short8 breg[18];
  {
    const short8* __restrict__ WB =
        (const short8*)Wt + ((size_t)(p * 4 + ot)) * 2304 + kg * 16 + c16;
#pragma unroll
    for (int j = 0; j < 18; ++j) breg[j] = WB[(size_t)(kq * 18 + j) * 64];
  }
  const float pb = pwb[o_g * NPIX + p];

  const int half = tid >> 8;                  // A-build half (wave-uniform)
  const int hb = (tid >> 4) & 15;             // batch
  const int m = tid & 15;                     // c-octet
  const int bm = hb * NC + m * 8;

  // ================= rollout =================
  for (int s = 0; s < N_ROLL; ++s) {
    const ushort_t* __restrict__ sgc = (s & 1) ? SgB : SgA;
    ushort_t* __restrict__ sgn = (s & 1) ? SgA : SgB;

    // ---- wait: 8 neighbor flags >= s (wave 0), then block barrier
    if (wv == 0) {
      while (true) {
        int f = 0x7fffffff;
        if (relevant)
          f = __hip_atomic_load(flags + faddr, __ATOMIC_RELAXED,
                                __HIP_MEMORY_SCOPE_AGENT);
        if (__all(!relevant || f >= s)) break;
        __builtin_amdgcn_s_sleep(1);
      }
    }
    __syncthreads();

    // ---- A-build: half0 stages q={0,2,4(center:LDS),6,8}, half1 q={1,3,5,7}
#pragma unroll
    for (int i = 0; i < 5; ++i) {
      if (half == 0 || i < 4) {
        const int q = 2 * i + half;
        short8 v;
        if (half == 0 && i == 2) {
          v = *(const short8*)&tmp[hb][m * 8];            // own state from LDS
        } else {
          const int ih = ph + q / 3 - 1, iw = pw_ + q % 3 - 1;
          union { u64 u[2]; short8 s8; } cv;
          cv.u[0] = 0; cv.u[1] = 0;
          if ((unsigned)ih < (unsigned)HH && (unsigned)iw < (unsigned)WW) {
            const u64* src =
                (const u64*)(sgc + (size_t)(ih * WW + iw) * (BATCH * NC) + bm);
            cv.u[0] = __hip_atomic_load(src, __ATOMIC_RELAXED,
                                        __HIP_MEMORY_SCOPE_AGENT);
            cv.u[1] = __hip_atomic_load(src + 1, __ATOMIC_RELAXED,
                                        __HIP_MEMORY_SCOPE_AGENT);
          }
          v = cv.s8;
        }
        const int rw_ = q * 16 + m;
        SA[rw_ * 16 + (hb ^ m)] = v;                      // XOR swizzle
      }
    }
    __syncthreads();

    // ---- 18 MFMAs: LDS A-frags x register B-frags
    f32x4 acc0 = {0.f, 0.f, 0.f, 0.f}, acc1 = {0.f, 0.f, 0.f, 0.f};
#pragma unroll
    for (int ii = 0; ii < 9; ++ii) {
      const int ks0 = kq * 18 + ii * 2;
      {
        const int r_ = ks0 * 4 + kg;
        acc0 = __builtin_amdgcn_mfma_f32_16x16x32_bf16(
            SA[r_ * 16 + (c16 ^ (r_ & 15))], breg[ii * 2], acc0, 0, 0, 0);
      }
      {
        const int r_ = (ks0 + 1) * 4 + kg;
        acc1 = __builtin_amdgcn_mfma_f32_16x16x32_bf16(
            SA[r_ * 16 + (c16 ^ (r_ & 15))], breg[ii * 2 + 1], acc1, 0, 0, 0);
      }
    }
    f32x4 acc = acc0 + acc1;

    // ---- cross-wave k-reduce + fused tanh state update (waves 0-3)
    if (wv >= 4) red[(wv - 4) * 64 + l] = acc;
    __syncthreads();
    if (wv < 4) {
      acc += red[wv * 64 + l];
#pragma unroll
      for (int r = 0; r < 4; ++r) {
        const float pre = acc[r] + pb;
        const float hz = hzr[r], hy = hyr[r];
        const float hzn = hz + DT * (tanhf(pre) - GAMMA * hy - EPSC * hz);
        const float hyn = hy + DT * hzn;
        hzr[r] = hzn;
        hyr[r] = hyn;
        if (s < N_ROLL - 1) {
          tmp[b0 + r][o_g] = f2bf(hzn);
          tmp[b0 + r][64 + o_g] = f2bf(hyn);
        }
      }
    }

    if (s < N_ROLL - 1) {
      __syncthreads();  // tmp ready
      // ---- publish S_{s+1}: coalesced relaxed u64 atomic stores
      {
        const int b = tid >> 5, ci = tid & 31;
        union { ushort_t us[4]; u64 u; } pk;
#pragma unroll
        for (int j2 = 0; j2 < 4; ++j2) pk.us[j2] = tmp[b][ci * 4 + j2];
        u64* dst = (u64*)(sgn + ((size_t)(p * BATCH + b)) * NC + ci * 4);
        __hip_atomic_store(dst, pk.u, __ATOMIC_RELAXED,
                           __HIP_MEMORY_SCOPE_AGENT);
      }
      __syncthreads();  // vmcnt(0) drained -> visible at L3
      if (tid == 0)
        __hip_atomic_store(flags + p * 16, s + 1, __ATOMIC_RELAXED,
                           __HIP_MEMORY_SCOPE_AGENT);
    }
  }

  // ================= readout (own pixel) -> d_out =================
  __syncthreads();
  if (wv < 4) {
#pragma unroll
    for (int r = 0; r < 4; ++r) hyf[b0 + r][o_g] = hyr[r];
  }
  __syncthreads();
  if (tid < BATCH * N_OUTC) {
    const int b = tid / N_OUTC, o = tid % N_OUTC;
    float acc2 = rob[o];
#pragma unroll 8
    for (int c2 = 0; c2 < 64; ++c2) acc2 += hyf[b][c2] * row[o * 64 + c2];
    out[((size_t)(b * N_OUTC + o)) * NPIX + p] = acc2;
  }
}

// ---------------------------------------------------------------------------
extern "C" void kernel_launch(void* const* d_in, const int* in_sizes, int n_in,
                              void* d_out, int out_size, void* d_ws, size_t ws_size,
                              hipStream_t stream) {
  const float* x         = (const float*)d_in[0];
  const float* readin_w  = (const float*)d_in[1];
  const float* readin_b  = (const float*)d_in[2];
  const float* pw_w      = (const float*)d_in[3];
  const float* pw_b      = (const float*)d_in[4];
  const float* readout_w = (const float*)d_in[5];
  const float* readout_b = (const float*)d_in[6];
  float* out = (float*)d_out;

  ushort_t* Wt  = (ushort_t*)d_ws;              // 8,847,360 bf16 = 17.7 MB
  ushort_t* Sg0 = Wt + (size_t)120 * 9216 * 8;  // 245,760 bf16
  ushort_t* Sg1 = Sg0 + 245760;
  int*      flg = (int*)(Sg1 + 245760);         // 120 x 64B-padded flags

  transpose2_kernel<<<4320, 256, 0, stream>>>(pw_w, Wt);

  {
    const ushort_t* aWt = Wt;
    ushort_t* aSgA = Sg0;
    ushort_t* aSgB = Sg1;
    const float* aX = x;
    const float* aRw = readin_w;
    const float* aRb = readin_b;
    const float* aPwb = pw_b;
    const float* aRow = readout_w;
    const float* aRob = readout_b;
    float* aOut = out;
    int* aFlg = flg;
    void* args[] = {(void*)&aWt, (void*)&aSgA, (void*)&aSgB, (void*)&aX,
                    (void*)&aRw, (void*)&aRb,  (void*)&aPwb, (void*)&aRow,
                    (void*)&aRob, (void*)&aOut, (void*)&aFlg};
    hipLaunchCooperativeKernel((const void*)persist6_kernel, dim3(NPIX),
                               dim3(512), args, 0, stream);
  }
}